// Round 9
// baseline (1226.964 us; speedup 1.0000x reference)
//
#include <hip/hip_runtime.h>

// WaveNet (nsynth batch-folding) on MI355X — persistent kernel, v9.
// Stream identity: batch-folding dilation == dilated conv over one 8192-sample
// stream, j = l*2 + n; fold-d taps at j +- 2d, zero-pad at stream ends.
//
// v9 = v5's PROVEN schedule (natural chunk order, taps 0/2 staged at layer
// start, tap1 written by the epilogue, ring-3 B DMA with counted vmcnt,
// post-loop cross-barrier prefetch) with ONE change: 16 waves per block
// (1024 threads, 4 waves/SIMD) for 2x latency hiding. H/S fp32 masters in
// registers; bf16 Hb mirror is the only per-layer global activation traffic.

#define TS 8192
#define NL 30
#define NBLK 256

typedef __attribute__((ext_vector_type(8))) short bf16x8;
typedef __attribute__((ext_vector_type(4))) float f32x4;

__device__ __forceinline__ unsigned short f2bf(float f) {
    union { float f; unsigned int u; } v; v.f = f;
    unsigned int u = v.u;
    u += 0x7fffu + ((u >> 16) & 1u);   // RNE
    return (unsigned short)(u >> 16);
}

__device__ __forceinline__ void gload_lds16(const void* g, void* l) {
    __builtin_amdgcn_global_load_lds(
        (const __attribute__((address_space(1))) void*)g,
        (__attribute__((address_space(3))) void*)l, 16, 0, 0);
}

#define VMW4()  asm volatile("s_waitcnt vmcnt(4)" ::: "memory")
#define VMW2()  asm volatile("s_waitcnt vmcnt(2)" ::: "memory")
#define VMW0()  asm volatile("s_waitcnt vmcnt(0)" ::: "memory")
#define LGKM0() asm volatile("s_waitcnt lgkmcnt(0)" ::: "memory")
#define SBAR()  __builtin_amdgcn_s_barrier()
#define MFMA16(a, b, c) __builtin_amdgcn_mfma_f32_16x16x32_bf16((a), (b), (c), 0, 0, 0)

__device__ __forceinline__ int swz_jb(int bid) {   // XCD-chunked j-tile map
    return ((bid & 7) << 5) | (bid >> 3);
}

// ---------------------------------------------------------------------------
// Weight prep: fp32 -> bf16 with layout transforms.
// Wgf[k][t][o][ci], o in [0,512): 0..255 gate, 256..511 feat (tap t split out)
// Wts[k][o][ci],    o in [0,512): 0..255 thru, 256..511 skip
// ---------------------------------------------------------------------------
__global__ void prep_weights_kernel(
    const float* __restrict__ gw, const float* __restrict__ fw,
    const float* __restrict__ tw, const float* __restrict__ sw,
    const float* __restrict__ iw, const float* __restrict__ fnw,
    unsigned short* __restrict__ Wgf, unsigned short* __restrict__ Wts,
    unsigned short* __restrict__ Wib, unsigned short* __restrict__ Wfb)
{
    const int idx = blockIdx.x * blockDim.x + threadIdx.x;
    const int stride = gridDim.x * blockDim.x;
    const int n_gf = NL * 3 * 512 * 256;
    for (int i = idx; i < n_gf; i += stride) {
        int ci = i & 255;
        int o  = (i >> 8) & 511;
        int r  = i >> 17;      // k*3 + t
        int t  = r % 3;
        int k  = r / 3;
        float v = (o < 256) ? gw[((k * 256 + o) * 256 + ci) * 3 + t]
                            : fw[((k * 256 + (o - 256)) * 256 + ci) * 3 + t];
        Wgf[i] = f2bf(v);
    }
    const int n_ts = NL * 512 * 256;
    for (int i = idx; i < n_ts; i += stride) {
        int ci = i & 255;
        int o  = (i >> 8) & 511;
        int k  = i >> 17;
        float v = (o < 256) ? tw[(k * 256 + o) * 256 + ci]
                            : sw[(k * 256 + (o - 256)) * 256 + ci];
        Wts[i] = f2bf(v);
    }
    for (int i = idx; i < 256 * 256; i += stride) Wib[i] = f2bf(iw[i]);
    for (int i = idx; i < 256 * 256; i += stride) Wfb[i] = f2bf(fnw[i]);
}

// ---------------------------------------------------------------------------
__device__ __forceinline__ void grid_barrier(unsigned* cnt, unsigned target, int tid) {
    __syncthreads();
    if (tid == 0) {
        __hip_atomic_fetch_add(cnt, 1u, __ATOMIC_RELEASE, __HIP_MEMORY_SCOPE_AGENT);
        while (__hip_atomic_load(cnt, __ATOMIC_RELAXED, __HIP_MEMORY_SCOPE_AGENT) < target)
            __builtin_amdgcn_s_sleep(2);
        (void)__hip_atomic_load(cnt, __ATOMIC_ACQUIRE, __HIP_MEMORY_SCOPE_AGENT);
    }
    __syncthreads();
}

// ---------------------------------------------------------------------------
// B-chunk staging, 16-wave. Chunk c in [0,32): c<24 -> Wgf tap t=c>>3, kc=c&7
// (gate rows 16v.., feat rows 256+16v..); c>=24 -> Wts kc=c-24 (rows 32v..).
// Per-wave slice: [wave][buf<3][1024 hw = 2KB]. Uniform LDS dest (DMA rule);
// 16B-slot XOR pre-swizzle on the SOURCE, undone at read (bread16).
// ---------------------------------------------------------------------------
__device__ __forceinline__ void stage16(
    const unsigned short* __restrict__ Wgf_k,
    const unsigned short* __restrict__ Wts_k,
    unsigned short* B_lds, int c, int buf, int v, int lane)
{
    const int rsub = lane >> 2;                       // 0..15 source row
    const int slot = (lane & 3) ^ ((lane >> 3) & 3);  // pre-swizzled src slot
    unsigned short* dst = B_lds + v * 3072 + buf * 1024;   // wave-uniform
    if (c < 24) {
        const int t = c >> 3, kc = c & 7;
        const unsigned short* Wb = Wgf_k + kc * 32 + slot * 8;
        gload_lds16(Wb + ((t * 512 + 16 * v + rsub) << 8), dst);
        gload_lds16(Wb + ((t * 512 + 256 + 16 * v + rsub) << 8), dst + 512);
    } else {
        const int kc = c - 24;
        const unsigned short* Wb = Wts_k + kc * 32 + slot * 8;
        gload_lds16(Wb + ((32 * v + rsub) << 8), dst);
        gload_lds16(Wb + ((32 * v + 16 + rsub) << 8), dst + 512);
    }
}

// read B fragment: local row r (0..31), k-quarter krow (0..3)
__device__ __forceinline__ bf16x8 bread16(const unsigned short* B_lds,
                                          int v, int buf, int r, int krow)
{
    return *(const bf16x8*)(B_lds + v * 3072 + buf * 1024 + r * 32 +
                            ((krow ^ ((r >> 1) & 3)) << 3));
}

// ---------------------------------------------------------------------------
__global__ __launch_bounds__(1024, 4)
void wavenet_kernel(const float* __restrict__ x,
                    const float* __restrict__ init_w,
                    const float* __restrict__ init_b,
                    const unsigned short* __restrict__ Wib,
                    const float* __restrict__ ib,
                    const unsigned short* __restrict__ Wgf,
                    const unsigned short* __restrict__ Wts,
                    const float* __restrict__ gbA,
                    const float* __restrict__ fbA,
                    const unsigned short* __restrict__ Wfb,
                    const float* __restrict__ fbias,
                    unsigned short* __restrict__ Hb0,
                    unsigned short* __restrict__ Hb1,
                    float* __restrict__ out,
                    unsigned* __restrict__ counter)
{
    __shared__ __align__(16) unsigned short A_lds[3 * 32 * 256];     // 48 KB
    __shared__ __align__(16) unsigned short B_lds[16 * 3 * 1024];    // 96 KB

    const int tid  = threadIdx.x;
    const int lane = tid & 63;
    const int v    = tid >> 6;          // wave 0..15
    const int j0   = swz_jb(blockIdx.x) * 32;
    const int arow = lane & 15;
    const int krow = lane >> 4;
    const int aswz = (arow & 7) << 4;

    // persistent fp32 masters: v<8 -> H cols [32v,32v+32); v>=8 -> S cols.
    f32x4 state[2][2];

    // ================= init conv -> state (waves 0-7), Hb0 + LDS tap1 ======
    if (v < 8) {
        const int c0 = v * 32;
        #pragma unroll
        for (int ct = 0; ct < 2; ++ct) {
            const int col = c0 + ct * 16 + arow;
            const float w0 = init_w[col * 3];
            const float w1 = init_w[col * 3 + 1];
            const float w2 = init_w[col * 3 + 2];
            const float b  = init_b[col];
            #pragma unroll
            for (int rt = 0; rt < 2; ++rt)
                #pragma unroll
                for (int i = 0; i < 4; ++i) {
                    const int row = rt * 16 + krow * 4 + i;
                    const int j = j0 + row;
                    float acc = b + w1 * x[(j & 1) * 4096 + (j >> 1)];
                    int i2 = j - 2;
                    if (i2 >= 0) acc += w0 * x[(i2 & 1) * 4096 + (i2 >> 1)];
                    i2 = j + 2;
                    if (i2 < TS) acc += w2 * x[(i2 & 1) * 4096 + (i2 >> 1)];
                    state[rt][ct][i] = acc;
                    const unsigned short hb = f2bf(acc);
                    Hb0[(j << 8) + col] = hb;
                    A_lds[((32 + row) << 8) + (((col << 1) ^ ((row & 7) << 4)) >> 1)] = hb;
                }
        }
    }
    LGKM0(); SBAR();   // H0 (bf16) visible in tap1

    // ================= iskip -> state (waves 8-15) =========================
    if (v >= 8) {
        const int cs = (v - 8) * 32;
        #pragma unroll
        for (int ct = 0; ct < 2; ++ct) {
            const float b = ib[cs + ct * 16 + arow];
            state[0][ct] = (f32x4){b, b, b, b};
            state[1][ct] = state[0][ct];
        }
        #pragma unroll
        for (int kc = 0; kc < 8; ++kc) {
            const int aoff = ((kc * 64 + krow * 16) ^ aswz) >> 1;
            const bf16x8 a0 = *(const bf16x8*)(A_lds + ((32 + arow) << 8) + aoff);
            const bf16x8 a1 = *(const bf16x8*)(A_lds + ((48 + arow) << 8) + aoff);
            const int koff = kc * 32 + krow * 8;
            const bf16x8 b0 = *(const bf16x8*)(Wib + ((cs + arow) << 8) + koff);
            const bf16x8 b1 = *(const bf16x8*)(Wib + ((cs + 16 + arow) << 8) + koff);
            state[0][0] = MFMA16(a0, b0, state[0][0]);
            state[1][0] = MFMA16(a1, b0, state[1][0]);
            state[0][1] = MFMA16(a0, b1, state[0][1]);
            state[1][1] = MFMA16(a1, b1, state[1][1]);
        }
    }

    // prefetch layer-0 chunks 0,1 (fly across the grid barrier)
    stage16(Wgf, Wts, B_lds, 0, 0, v, lane);
    stage16(Wgf, Wts, B_lds, 1, 1, v, lane);

    unsigned target = NBLK;
    grid_barrier(counter, target, tid);

    const unsigned short* Hb_in = Hb0;
    unsigned short*       Hb_out = Hb1;

    // ============================ layer loop ================================
    for (int k = 0; k < NL; ++k) {
        const int d = 2 << (k % 10);   // stream dilation = 2 * 2^(k%10)
        const unsigned short* Wgf_k = Wgf + (size_t)k * 393216;
        const unsigned short* Wts_k = Wts + (size_t)k * 131072;

        // ---- A-stage: taps 0 and 2 from global (center tap already in tap1)
        #pragma unroll
        for (int q = 0; q < 2; ++q) {
            const int cc  = tid + q * 1024;
            const int c16 = cc & 31;
            const int m   = (cc >> 5) & 31;
            const int t   = (cc >> 10) << 1;            // 0 or 2
            const int r   = j0 + m + (t - 1) * d;
            uint4 val = make_uint4(0u, 0u, 0u, 0u);
            if (r >= 0 && r < TS)
                val = *(const uint4*)(Hb_in + (r << 8) + (c16 << 3));
            const int sb = ((c16 << 4) ^ ((m & 7) << 4)) >> 1;
            *(uint4*)(A_lds + ((t * 32 + m) << 8) + sb) = val;
        }
        LGKM0(); SBAR();   // A complete (chunks 0,1 DMA already landed)

        // ---- phase 1: chunks 0..23 (taps 0,1,2), ring-3, depth-2 vmcnt ----
        const float gv = gbA[k * 256 + v * 16 + arow];
        const float fv = fbA[k * 256 + v * 16 + arow];
        f32x4 accG[2], accF[2];
        accG[0] = (f32x4){gv, gv, gv, gv}; accG[1] = accG[0];
        accF[0] = (f32x4){fv, fv, fv, fv}; accF[1] = accF[0];

        #pragma unroll
        for (int c = 0; c < 24; ++c) {
            stage16(Wgf_k, Wts_k, B_lds, c + 2, (c + 2) % 3, v, lane);
            VMW4();                                     // chunk c landed
            const int t = c >> 3, kc = c & 7;
            const int aoff = ((kc * 64 + krow * 16) ^ aswz) >> 1;
            const unsigned short* At = A_lds + ((t * 32 + arow) << 8);
            const bf16x8 a0 = *(const bf16x8*)(At + aoff);
            const bf16x8 a1 = *(const bf16x8*)(At + (16 << 8) + aoff);
            const int buf = c % 3;
            const bf16x8 bg  = bread16(B_lds, v, buf, arow, krow);
            const bf16x8 bf_ = bread16(B_lds, v, buf, 16 + arow, krow);
            accG[0] = MFMA16(a0, bg,  accG[0]);
            accG[1] = MFMA16(a1, bg,  accG[1]);
            accF[0] = MFMA16(a0, bf_, accF[0]);
            accF[1] = MFMA16(a1, bf_, accF[1]);
        }

        LGKM0(); SBAR();   // all conv tap reads done (tap0 reused for res)

        // ---- res = sigmoid(G)*tanh(F) -> tap0 (swizzled) ----
        #pragma unroll
        for (int rt = 0; rt < 2; ++rt)
            #pragma unroll
            for (int i = 0; i < 4; ++i) {
                const float g = accG[rt][i];
                const float f = accF[rt][i];
                const float sg = 1.0f / (1.0f + __expf(-g));
                const float e2 = __expf(2.0f * f);
                const float th = 1.0f - 2.0f / (e2 + 1.0f);
                const float rr = sg * th;
                const int row = rt * 16 + krow * 4 + i;
                const int col = v * 16 + arow;
                A_lds[(row << 8) + (((col << 1) ^ ((row & 7) << 4)) >> 1)] = f2bf(rr);
            }
        LGKM0(); SBAR();   // res visible (chunks 24,25 in flight)

        // ---- phase 2: chunks 24..31; acc starts from persistent state ----
        f32x4 acc2[2][2];
        #pragma unroll
        for (int rt = 0; rt < 2; ++rt)
            #pragma unroll
            for (int ct = 0; ct < 2; ++ct)
                acc2[rt][ct] = state[rt][ct];

        #pragma unroll
        for (int p = 0; p < 8; ++p) {
            if (p < 6)      { stage16(Wgf_k, Wts_k, B_lds, 26 + p, (26 + p) % 3, v, lane); VMW4(); }
            else if (p == 6){ VMW2(); }
            else            { VMW0(); }
            const int aoff = ((p * 64 + krow * 16) ^ aswz) >> 1;
            const bf16x8 a0 = *(const bf16x8*)(A_lds + (arow << 8) + aoff);
            const bf16x8 a1 = *(const bf16x8*)(A_lds + ((16 + arow) << 8) + aoff);
            const int buf = p % 3;
            const bf16x8 b0 = bread16(B_lds, v, buf, arow, krow);
            const bf16x8 b1 = bread16(B_lds, v, buf, 16 + arow, krow);
            acc2[0][0] = MFMA16(a0, b0, acc2[0][0]);
            acc2[1][0] = MFMA16(a1, b0, acc2[1][0]);
            acc2[0][1] = MFMA16(a0, b1, acc2[0][1]);
            acc2[1][1] = MFMA16(a1, b1, acc2[1][1]);
        }

        // ---- state update (registers only) ----
        #pragma unroll
        for (int rt = 0; rt < 2; ++rt)
            #pragma unroll
            for (int ct = 0; ct < 2; ++ct)
                state[rt][ct] = acc2[rt][ct];

        if (k < NL - 1) {
            // prefetch next layer's chunks 0,1 into bufs 0,1 — AFTER the
            // phase-2 loop (bufs 0,1 were read at p=6,7). DMA flies under the
            // epilogue + barrier wait; the barrier's syncthreads drains it.
            stage16(Wgf_k + 393216, Wts_k + 131072, B_lds, 0, 0, v, lane);
            stage16(Wgf_k + 393216, Wts_k + 131072, B_lds, 1, 1, v, lane);

            // waves 0-7: publish bf16 H to global (halo) + LDS tap1 (center)
            if (v < 8) {
                #pragma unroll
                for (int rt = 0; rt < 2; ++rt)
                    #pragma unroll
                    for (int ct = 0; ct < 2; ++ct)
                        #pragma unroll
                        for (int i = 0; i < 4; ++i) {
                            const int row = rt * 16 + krow * 4 + i;
                            const int col = v * 32 + ct * 16 + arow;
                            const unsigned short hb = f2bf(state[rt][ct][i]);
                            Hb_out[((j0 + row) << 8) + col] = hb;
                            A_lds[((32 + row) << 8) + (((col << 1) ^ ((row & 7) << 4)) >> 1)] = hb;
                        }
            }
            target += NBLK;
            grid_barrier(counter, target, tid);   // drains prefetch + publishes H

            unsigned short* tmp = (unsigned short*)Hb_in;
            Hb_in = Hb_out; Hb_out = tmp;
        } else {
            // last layer: S (waves 8-15) -> tap0 bf16 for the final GEMM
            LGKM0(); SBAR();   // all phase-2 tap0 reads done
            if (v >= 8) {
                #pragma unroll
                for (int rt = 0; rt < 2; ++rt)
                    #pragma unroll
                    for (int ct = 0; ct < 2; ++ct)
                        #pragma unroll
                        for (int i = 0; i < 4; ++i) {
                            const int row = rt * 16 + krow * 4 + i;
                            const int col = (v - 8) * 32 + ct * 16 + arow;
                            A_lds[(row << 8) + (((col << 1) ^ ((row & 7) << 4)) >> 1)] =
                                f2bf(state[rt][ct][i]);
                        }
            }
            LGKM0(); SBAR();
        }
    }

    // ================= final: out = Wfb @ S^T + fbias =======================
    {
        const int m0 = v * 16;   // co slice, 16 per wave
        f32x4 facc[2];
        facc[0] = (f32x4){0.f, 0.f, 0.f, 0.f};
        facc[1] = facc[0];

        #pragma unroll
        for (int kc = 0; kc < 8; ++kc) {
            const int koff = kc * 32 + krow * 8;
            const bf16x8 a0 = *(const bf16x8*)(Wfb + ((m0 + arow) << 8) + koff);
            const int aoff = ((kc * 64 + krow * 16) ^ aswz) >> 1;
            const bf16x8 b0 = *(const bf16x8*)(A_lds + (arow << 8) + aoff);
            const bf16x8 b1 = *(const bf16x8*)(A_lds + ((16 + arow) << 8) + aoff);
            facc[0] = MFMA16(a0, b0, facc[0]);
            facc[1] = MFMA16(a0, b1, facc[1]);
        }

        #pragma unroll
        for (int ct = 0; ct < 2; ++ct)
            #pragma unroll
            for (int i = 0; i < 4; ++i) {
                const int co = m0 + krow * 4 + i;
                const int jj = j0 + ct * 16 + arow;
                out[((jj & 1) << 20) + (co << 12) + (jj >> 1)] = facc[ct][i] + fbias[co];
            }
    }
}

// ---------------------------------------------------------------------------
extern "C" void kernel_launch(void* const* d_in, const int* in_sizes, int n_in,
                              void* d_out, int out_size, void* d_ws, size_t ws_size,
                              hipStream_t stream)
{
    const float* x       = (const float*)d_in[0];
    const float* init_w  = (const float*)d_in[1];
    const float* init_b  = (const float*)d_in[2];
    const float* iskip_w = (const float*)d_in[3];
    const float* iskip_b = (const float*)d_in[4];
    const float* gate_w  = (const float*)d_in[5];
    const float* gate_b  = (const float*)d_in[6];
    const float* feat_w  = (const float*)d_in[7];
    const float* feat_b  = (const float*)d_in[8];
    const float* skip_w  = (const float*)d_in[9];
    const float* thru_w  = (const float*)d_in[10];
    const float* final_w = (const float*)d_in[11];
    const float* final_b = (const float*)d_in[12];

    char* ws = (char*)d_ws;
    size_t off = 0;
    auto alloc = [&](size_t bytes) {
        void* p = ws + off;
        off += (bytes + 255) & ~(size_t)255;
        return p;
    };
    unsigned short* Wgf = (unsigned short*)alloc((size_t)NL * 3 * 512 * 256 * 2);
    unsigned short* Wts = (unsigned short*)alloc((size_t)NL * 512 * 256 * 2);
    unsigned short* Wib = (unsigned short*)alloc(256 * 256 * 2);
    unsigned short* Wfb = (unsigned short*)alloc(256 * 256 * 2);
    unsigned short* Hb0 = (unsigned short*)alloc((size_t)TS * 256 * 2);
    unsigned short* Hb1 = (unsigned short*)alloc((size_t)TS * 256 * 2);
    unsigned*       cnt = (unsigned*)alloc(256);

    hipMemsetAsync((void*)cnt, 0, 256, stream);
    prep_weights_kernel<<<2048, 256, 0, stream>>>(gate_w, feat_w, thru_w, skip_w,
                                                  iskip_w, final_w, Wgf, Wts, Wib, Wfb);
    wavenet_kernel<<<NBLK, 1024, 0, stream>>>(
        x, init_w, init_b, Wib, iskip_b, Wgf, Wts, gate_b, feat_b,
        Wfb, final_b, Hb0, Hb1, (float*)d_out, cnt);
}